// Round 2
// baseline (756.018 us; speedup 1.0000x reference)
//
#include <hip/hip_runtime.h>
#include <math.h>

// Problem constants (from reference)
#define N_NODES 100000
#define C_CL 30
#define D_IN 256

// d_out float offsets: (out, mincut, ortho, Z, S) concatenated
#define OUT_MAT 0        // 30*64
#define OUT_MC 1920
#define OUT_OR 1921
#define OUT_Z 1922       // 30*256
#define OUT_S 9602       // N*30

// ws float offsets
#define WS_M 0           // 30*256  (M = S^T x)
#define WS_SS 7680       // 30*30
#define WS_CS 8580       // 30 (colsum S)
#define WS_CUT 8610      // 1
#define WS_ZERO_CNT 8611 // zero range [0, 8611)
#define WS_H1 8640       // 30*256
#define WS_H2 16320      // 30*256
#define WS_WT4 24000     // 64*30 float4 = 7680 floats (W grouped by k4)
#define WS_S16 32000     // bf16 padded S: 100032 rows * 16 dwords (as uint)

// ---------------------------------------------------------------------------
// prep: build WT4[k4][c] = (W[4k4+0][c],...,W[4k4+3][c]) and zero accumulators
__global__ __launch_bounds__(256)
void k_prep(const float* __restrict__ Wa, float* __restrict__ ws) {
  const int b = blockIdx.x, t = threadIdx.x;
  if (b < 8) {
    const int g = b * 256 + t;
    if (g < 64 * C_CL) {
      const int k4 = g / C_CL, c = g - C_CL * k4;
      float4 v;
      v.x = Wa[(4 * k4 + 0) * C_CL + c];
      v.y = Wa[(4 * k4 + 1) * C_CL + c];
      v.z = Wa[(4 * k4 + 2) * C_CL + c];
      v.w = Wa[(4 * k4 + 3) * C_CL + c];
      reinterpret_cast<float4*>(ws + WS_WT4)[g] = v;
    }
  } else {
    for (int i = t; i < WS_ZERO_CNT; i += 256) ws[i] = 0.f;
  }
}

// ---------------------------------------------------------------------------
// Thread-per-node: logits via wave-uniform W loads, softmax in registers,
// write packed fp32 S and 64B-per-row bf16 S.
__global__ __launch_bounds__(64)
void k_node(const float* __restrict__ x, const float* __restrict__ wt4f,
            const float* __restrict__ ba, float* __restrict__ S_out,
            unsigned* __restrict__ S16) {
  __shared__ float st[64][33];   // +1 pad breaks write conflicts
  const int t = threadIdx.x;
  const int node = blockIdx.x * 64 + t;
  const float4* __restrict__ x4 = reinterpret_cast<const float4*>(x);
  const float4* __restrict__ wt4 = reinterpret_cast<const float4*>(wt4f);

  float acc[C_CL];
  #pragma unroll
  for (int c = 0; c < C_CL; ++c) acc[c] = 0.f;

  if (node < N_NODES) {
    #pragma unroll 4
    for (int k4 = 0; k4 < 64; ++k4) {
      const float4 xv = x4[(size_t)node * 64 + k4];
      #pragma unroll
      for (int c = 0; c < C_CL; ++c) {
        const float4 wv = wt4[k4 * C_CL + c];   // wave-uniform -> s_load/broadcast
        acc[c] += xv.x * wv.x + xv.y * wv.y + xv.z * wv.z + xv.w * wv.w;
      }
    }
    float mx = -3.0e38f;
    #pragma unroll
    for (int c = 0; c < C_CL; ++c) { acc[c] += ba[c]; mx = fmaxf(mx, acc[c]); }
    float sm = 0.f;
    #pragma unroll
    for (int c = 0; c < C_CL; ++c) { acc[c] = __expf(acc[c] - mx); sm += acc[c]; }
    const float r = 1.f / sm;
    #pragma unroll
    for (int c = 0; c < C_CL; ++c) acc[c] *= r;
  }
  #pragma unroll
  for (int c = 0; c < C_CL; ++c) st[t][c] = acc[c];
  st[t][30] = 0.f; st[t][31] = 0.f;
  __syncthreads();

  // packed fp32 S: block chunk is contiguous (64 rows * 30 floats)
  const int gbase = blockIdx.x * 1920;
  #pragma unroll
  for (int i = 0; i < 30; ++i) {
    const unsigned idx = i * 64 + t;
    const unsigned n = idx / 30u, c = idx - 30u * n;
    const int g = gbase + (int)idx;
    if (g < N_NODES * C_CL) S_out[g] = st[n][c];
  }
  // bf16 padded S: 64 rows * 16 dwords (row = one 64B cache line)
  const unsigned sbase = blockIdx.x * 1024;
  #pragma unroll
  for (int i = 0; i < 16; ++i) {
    const unsigned idx = i * 64 + t;
    const unsigned n = idx >> 4, j = idx & 15;
    const unsigned lo = __float_as_uint(st[n][j * 2]);
    const unsigned hi = __float_as_uint(st[n][j * 2 + 1]);
    const unsigned lo16 = (lo + 0x7fffu + ((lo >> 16) & 1u)) >> 16;
    const unsigned hi16 = (hi + 0x7fffu + ((hi >> 16) & 1u)) >> 16;
    S16[sbase + idx] = lo16 | (hi16 << 16);
  }
}

// ---------------------------------------------------------------------------
// M = S^T x (+ fused SS = S^T S and colsum): block = 256-node chunk.
__global__ __launch_bounds__(256)
void k_M(const float* __restrict__ x, const float* __restrict__ Sp,
         float* __restrict__ ws) {
  __shared__ float sm[256][32];
  const int t = threadIdx.x;
  const int node0 = blockIdx.x * 256;

  // stage packed S chunk (coalesced) into padded LDS
  #pragma unroll
  for (int i = 0; i < 30; ++i) {
    const unsigned idx = i * 256 + t;
    const unsigned n = idx / 30u, c = idx - 30u * n;
    const int g = node0 * C_CL + (int)idx;
    sm[n][c] = (g < N_NODES * C_CL) ? Sp[g] : 0.f;
  }
  sm[t][30] = 0.f; sm[t][31] = 0.f;
  __syncthreads();

  // ---- M: thread = (c-half h, node-half sub, 4 cols) ----
  const int h = t >> 7, sub = (t >> 6) & 1;
  const int lc = t & 63;               // x4 column index (cols lc*4..lc*4+3)
  float a[16][4];
  #pragma unroll
  for (int j = 0; j < 16; ++j) { a[j][0] = 0.f; a[j][1] = 0.f; a[j][2] = 0.f; a[j][3] = 0.f; }
  const float4* __restrict__ x4 = reinterpret_cast<const float4*>(x);
  const int rows_valid = N_NODES - node0;

  for (int n = 0; n < 128; ++n) {
    const int nn = sub * 128 + n;
    float4 xv = make_float4(0.f, 0.f, 0.f, 0.f);
    if (nn < rows_valid) xv = x4[(size_t)(node0 + nn) * 64 + lc];
    const float4 s0 = *reinterpret_cast<const float4*>(&sm[nn][h * 16 + 0]);
    const float4 s1 = *reinterpret_cast<const float4*>(&sm[nn][h * 16 + 4]);
    const float4 s2 = *reinterpret_cast<const float4*>(&sm[nn][h * 16 + 8]);
    const float4 s3 = *reinterpret_cast<const float4*>(&sm[nn][h * 16 + 12]);
    const float sv[16] = {s0.x, s0.y, s0.z, s0.w, s1.x, s1.y, s1.z, s1.w,
                          s2.x, s2.y, s2.z, s2.w, s3.x, s3.y, s3.z, s3.w};
    #pragma unroll
    for (int j = 0; j < 16; ++j) {
      a[j][0] += sv[j] * xv.x; a[j][1] += sv[j] * xv.y;
      a[j][2] += sv[j] * xv.z; a[j][3] += sv[j] * xv.w;
    }
  }
  #pragma unroll
  for (int j = 0; j < 16; ++j) {
    const int c = h * 16 + j;
    if (c < C_CL) {
      #pragma unroll
      for (int q = 0; q < 4; ++q)
        atomicAdd(&ws[WS_M + c * 256 + lc * 4 + q], a[j][q]);
    }
  }

  // ---- SS: thread = (i4,j4) 4x4 block; wave w covers nodes w*64..w*64+63 ----
  const int i4 = (t >> 3) & 7, j4 = t & 7, w = t >> 6;
  float ssq[16];
  #pragma unroll
  for (int j = 0; j < 16; ++j) ssq[j] = 0.f;
  for (int n = 0; n < 64; ++n) {
    const int nn = w * 64 + n;
    const float4 av = *reinterpret_cast<const float4*>(&sm[nn][i4 * 4]);
    const float4 bv = *reinterpret_cast<const float4*>(&sm[nn][j4 * 4]);
    const float af[4] = {av.x, av.y, av.z, av.w};
    const float bf[4] = {bv.x, bv.y, bv.z, bv.w};
    #pragma unroll
    for (int ii = 0; ii < 4; ++ii)
      #pragma unroll
      for (int jj = 0; jj < 4; ++jj) ssq[ii * 4 + jj] += af[ii] * bf[jj];
  }
  #pragma unroll
  for (int ii = 0; ii < 4; ++ii) {
    #pragma unroll
    for (int jj = 0; jj < 4; ++jj) {
      const int gi = i4 * 4 + ii, gj = j4 * 4 + jj;
      if (gi < C_CL && gj < C_CL)
        atomicAdd(&ws[WS_SS + gi * C_CL + gj], ssq[ii * 4 + jj]);
    }
  }
  if (t < C_CL) {
    float cs = 0.f;
    for (int n = 0; n < 256; ++n) cs += sm[n][t];
    atomicAdd(&ws[WS_CS + t], cs);
  }
}

// ---------------------------------------------------------------------------
// cut = sum_e dot(S[r], S[c]); bf16 rows (one 64B line each), wave-cooperative:
// lane = (edge_sub * 4 + 16B-part); 16 edges per wave per iteration.
__device__ __forceinline__ float blo(unsigned u) { return __uint_as_float(u << 16); }
__device__ __forceinline__ float bhi(unsigned u) { return __uint_as_float(u & 0xffff0000u); }

__global__ __launch_bounds__(256)
void k_edges(const int* __restrict__ ei, const int E,
             const unsigned* __restrict__ S16, float* __restrict__ ws) {
  const int t = threadIdx.x;
  const int lane = t & 63;
  const int el = lane >> 2, part = lane & 3;
  const int gw = (blockIdx.x * 256 + t) >> 6;
  const int nw = gridDim.x * 4;
  const int* __restrict__ row = ei;
  const int* __restrict__ col = ei + E;
  float acc = 0.f;
  for (int base = gw * 16; base < E; base += nw * 16) {
    const int e = base + el;
    float d = 0.f;
    if (e < E) {
      const int r = row[e], c = col[e];
      const uint4 ur = *reinterpret_cast<const uint4*>(S16 + (size_t)r * 16 + part * 4);
      const uint4 uc = *reinterpret_cast<const uint4*>(S16 + (size_t)c * 16 + part * 4);
      d  = blo(ur.x) * blo(uc.x) + bhi(ur.x) * bhi(uc.x);
      d += blo(ur.y) * blo(uc.y) + bhi(ur.y) * bhi(uc.y);
      d += blo(ur.z) * blo(uc.z) + bhi(ur.z) * bhi(uc.z);
      d += blo(ur.w) * blo(uc.w) + bhi(ur.w) * bhi(uc.w);
    }
    d += __shfl_xor(d, 1, 64);   // quad sum
    d += __shfl_xor(d, 2, 64);
    acc += d;                    // identical within quad
  }
  // sum across the 16 quads (xor masks 4..32 keep part fixed -> each quad once)
  #pragma unroll
  for (int m = 4; m < 64; m <<= 1) acc += __shfl_xor(acc, m, 64);
  __shared__ float wsum[4];
  if (lane == 0) wsum[t >> 6] = acc;
  __syncthreads();
  if (t == 0)
    atomicAdd(&ws[WS_CUT], wsum[0] + wsum[1] + wsum[2] + wsum[3]);
}

// ---------------------------------------------------------------------------
// Z = M @ W_proj + colsum(S) (x) b_proj
__global__ __launch_bounds__(256)
void k_z(const float* __restrict__ ws, const float* __restrict__ Wp,
         const float* __restrict__ bp, float* __restrict__ out) {
  const int r = blockIdx.x, t = threadIdx.x;
  const float* m = ws + WS_M + r * 256;
  float acc = ws[WS_CS + r] * bp[t];
  #pragma unroll 8
  for (int k = 0; k < 256; ++k) acc += m[k] * Wp[(size_t)k * 256 + t];
  out[OUT_Z + r * 256 + t] = acc;
}

// ---------------------------------------------------------------------------
// Shapley layer (mask=ones, n=30): h = relu((in + colsum(in)/30) @ W)
__global__ __launch_bounds__(256)
void k_shlayer(const float* __restrict__ in, const float* __restrict__ W,
               float* __restrict__ outp) {
  __shared__ float sh[256];
  const int r = blockIdx.x, t = threadIdx.x;
  float cs = 0.f;
  #pragma unroll
  for (int i = 0; i < C_CL; ++i) cs += in[i * 256 + t];
  sh[t] = in[r * 256 + t] + (1.f / 30.f) * cs;
  __syncthreads();
  float acc = 0.f;
  #pragma unroll 8
  for (int k = 0; k < 256; ++k) acc += sh[k] * W[(size_t)k * 256 + t];
  outp[r * 256 + t] = fmaxf(acc, 0.f);
}

// ---------------------------------------------------------------------------
// out = h2 @ W_out + b_out ; block 30: mincut + ortho scalars
__global__ __launch_bounds__(64)
void k_out(const float* __restrict__ ws, const float* __restrict__ Wo,
           const float* __restrict__ bo, float* __restrict__ out,
           const float vol) {
  const int r = blockIdx.x, t = threadIdx.x;
  if (r < C_CL) {
    const float* hrow = ws + WS_H2 + r * 256;
    float acc = bo[t];
    #pragma unroll 8
    for (int k = 0; k < 256; ++k) acc += hrow[k] * Wo[k * 64 + t];
    out[OUT_MAT + r * 64 + t] = acc;
  } else {
    float s = 0.f;
    for (int i = t; i < C_CL * C_CL; i += 64) {
      const float d = ws[WS_SS + i] - ((i / C_CL == i % C_CL) ? 1.f : 0.f);
      s += d * d;
    }
    #pragma unroll
    for (int m = 32; m >= 1; m >>= 1) s += __shfl_xor(s, m, 64);
    if (t == 0) {
      out[OUT_OR] = sqrtf(s);
      out[OUT_MC] = -ws[WS_CUT] / (vol + 1e-9f);
    }
  }
}

// ---------------------------------------------------------------------------
extern "C" void kernel_launch(void* const* d_in, const int* in_sizes, int n_in,
                              void* d_out, int out_size, void* d_ws, size_t ws_size,
                              hipStream_t stream) {
  (void)n_in; (void)out_size; (void)ws_size;
  const float* x  = (const float*)d_in[0];
  const int*   ei = (const int*)d_in[1];
  const float* Wa = (const float*)d_in[2];
  const float* ba = (const float*)d_in[3];
  const float* Wp = (const float*)d_in[4];
  const float* bp = (const float*)d_in[5];
  const float* W1 = (const float*)d_in[6];
  const float* W2 = (const float*)d_in[7];
  const float* Wo = (const float*)d_in[8];
  const float* bo = (const float*)d_in[9];
  float* out = (float*)d_out;
  float* ws  = (float*)d_ws;
  unsigned* S16 = (unsigned*)(ws + WS_S16);
  const int E = in_sizes[1] / 2;

  k_prep<<<9, 256, 0, stream>>>(Wa, ws);
  k_node<<<1563, 64, 0, stream>>>(x, ws + WS_WT4, ba, out + OUT_S, S16);
  k_M<<<391, 256, 0, stream>>>(x, out + OUT_S, ws);
  k_edges<<<1024, 256, 0, stream>>>(ei, E, S16, ws);
  k_z<<<C_CL, 256, 0, stream>>>(ws, Wp, bp, out);
  k_shlayer<<<C_CL, 256, 0, stream>>>(out + OUT_Z, W1, ws + WS_H1);
  k_shlayer<<<C_CL, 256, 0, stream>>>(ws + WS_H1, W2, ws + WS_H2);
  k_out<<<C_CL + 1, 64, 0, stream>>>(ws, Wo, bo, out, (float)E);
}